// Round 2
// 3585.903 us; speedup vs baseline: 1.8402x; 1.8402x over previous
//
#include <hip/hip_runtime.h>

// nBRC recurrent cell, B=64, L=512, IN=512, MEM=1024.
// Phase 1: E[32768][3072] = u @ W_im^T, bf16x3 split-precision MFMA (unchanged).
// Phase 2: 512-step scan, persistent kernel, 256 blocks = 4 independent groups
//   of 64 (group g owns batches [g*16,+16)). Block (bg,cg): 16 batches x 32
//   W-rows {j0..j0+15, 1024+j0..+15}, j0=cg*16; W hi/lo bf16 VGPR-resident.
//
// Sync (round-5 redesign, round-6 adds bounded-spin diagnostics):
//   SELF-VALIDATING h WORDS, no flags, no release.
//   Old path per step: store h -> s_waitcnt(0) drain -> __syncthreads ->
//   tid0 AGENT-RELEASE flag (buffer_wbl2 + vmcnt(0) + store) -> consumer
//   flag poll -> h load.  ~4 serialized fabric round trips plus 256
//   buffer_wbl2 L2-walks per step; rocprof showed all pipes <4% busy, i.e.
//   the scan was pure sync latency (11.75 us/step).
//   New path: the 2 LSBs of the lo-split bf16 carry a step tag (t+1)&3.
//   Producer stores tagged h words fire-and-forget (sc0sc1, relaxed SYSTEM).
//   Consumer validates EVERY loaded word's tag (both dwords of each u64)
//   against t&3 and retries until all match.  Correctness:
//   - 4B stores are atomic; tags checked per dword -> torn u64 reads detected.
//   - ping-pong slot can only hold generation t or t-2 (skew<=1, induction:
//     every block validates the FULL group h each step before its barrier and
//     only stores tag-(t+1) after it; so a producer overwrites its slot with
//     tag t+2 only after validating everyone's t+1 words, which implies every
//     reader finished its tag-t reads).  2-bit tag separates t from t-2.
//   - hbuf memset 0 => tag 0 == expected tag at t=0, h0=+0. Self-consistent.
//   Tag perturbation of lo <= 3 ulp ~ h*2^-14, invisible vs 3.9e-3 absmax.
//   BOUNDED SPINS (diagnostic): canary loop caps at 3000 spins, validated-load
//   loop at 1000 (normal waits are <10 spins; bound never trips when sync is
//   correct). If the sync scheme is wrong, the kernel TERMINATES with stale h
//   -> harness reports passed:false + absmax + counters instead of an opaque
//   container timeout. Worst-case added time if fully deadlocked ~4 s/launch.
// part[] LDS is ping-ponged by t&1 -> ONE __syncthreads per step (barrier(t+1)
// separates read(t) from write(t+2)).  E prefetched one step ahead into regs.
// Workspace layout (bytes):
//   [0, 402653184)            E (fp32)
//   [402653184, +524288)      hbuf: [2 pingpong][64][1024] packed (bf16 hi | lo<<16)
// Precision: GEMMs = hi*hi + lo*hi + hi*lo (bf16 splits), fp32 accum; h carried
// fp32 in owner registers. Fast __expf-based tanh/sigmoid (~1e-6 err).

typedef __attribute__((ext_vector_type(8))) short short8;
typedef __attribute__((ext_vector_type(4))) float floatx4;

#define WS_HBUF_OFF 402653184UL

__device__ __forceinline__ unsigned short f2bf(float x) {
  unsigned u = __float_as_uint(x);
  unsigned r = (u + 0x7fffu + ((u >> 16) & 1u)) >> 16;  // RTN-even
  return (unsigned short)r;
}
__device__ __forceinline__ float bf2f(unsigned short h) {
  return __uint_as_float(((unsigned)h) << 16);
}
__device__ __forceinline__ float fast_tanh(float x) {
  x = fminf(15.0f, fmaxf(-15.0f, x));
  const float e = __expf(2.0f * x);
  return (e - 1.0f) / (e + 1.0f);
}
__device__ __forceinline__ float fast_sigmoid(float x) {
  return 1.0f / (1.0f + __expf(-x));
}

// ---------------------------------------------------------------------------
// Phase 1: E = U (32768x512, K-major) @ Wim^T (3072x512, K-major), fp32 out.
// ---------------------------------------------------------------------------
__global__ void __launch_bounds__(256, 2) gemm_in_proj(
    const float* __restrict__ U, const float* __restrict__ Wim,
    float* __restrict__ E)
{
  __shared__ unsigned short Ah[128][40], Al[128][40], Bh[128][40], Bl[128][40];
  const int tid = threadIdx.x;
  const int rbase = blockIdx.x * 128;
  const int nbase = blockIdx.y * 128;
  const int wave = tid >> 6, lane = tid & 63;
  const int wm = wave & 1, wn = wave >> 1;
  const int q = lane >> 4, ln = lane & 15;

  floatx4 acc[4][4];
#pragma unroll
  for (int mt = 0; mt < 4; ++mt)
#pragma unroll
    for (int nt = 0; nt < 4; ++nt)
      acc[mt][nt] = (floatx4){0.f, 0.f, 0.f, 0.f};

  for (int kc = 0; kc < 16; ++kc) {
    __syncthreads();
#pragma unroll
    for (int i = tid; i < 1024; i += 256) {
      const int row = i >> 3, c4 = (i & 7) << 2;
      const float4 va = *(const float4*)(U + (rbase + row) * 512 + kc * 32 + c4);
      const unsigned short a0 = f2bf(va.x), a1 = f2bf(va.y), a2 = f2bf(va.z), a3 = f2bf(va.w);
      *(ushort4*)&Ah[row][c4] = make_ushort4(a0, a1, a2, a3);
      *(ushort4*)&Al[row][c4] = make_ushort4(f2bf(va.x - bf2f(a0)), f2bf(va.y - bf2f(a1)),
                                             f2bf(va.z - bf2f(a2)), f2bf(va.w - bf2f(a3)));
      const float4 vb = *(const float4*)(Wim + (nbase + row) * 512 + kc * 32 + c4);
      const unsigned short b0 = f2bf(vb.x), b1 = f2bf(vb.y), b2 = f2bf(vb.z), b3 = f2bf(vb.w);
      *(ushort4*)&Bh[row][c4] = make_ushort4(b0, b1, b2, b3);
      *(ushort4*)&Bl[row][c4] = make_ushort4(f2bf(vb.x - bf2f(b0)), f2bf(vb.y - bf2f(b1)),
                                             f2bf(vb.z - bf2f(b2)), f2bf(vb.w - bf2f(b3)));
    }
    __syncthreads();

    short8 ah[4], al[4], bh[4], bl2[4];
#pragma unroll
    for (int mt = 0; mt < 4; ++mt) {
      const int m = wm * 64 + mt * 16 + ln;
      ah[mt] = *(const short8*)&Ah[m][q * 8];
      al[mt] = *(const short8*)&Al[m][q * 8];
    }
#pragma unroll
    for (int nt = 0; nt < 4; ++nt) {
      const int n = wn * 64 + nt * 16 + ln;
      bh[nt]  = *(const short8*)&Bh[n][q * 8];
      bl2[nt] = *(const short8*)&Bl[n][q * 8];
    }
#pragma unroll
    for (int mt = 0; mt < 4; ++mt)
#pragma unroll
      for (int nt = 0; nt < 4; ++nt) {
        acc[mt][nt] = __builtin_amdgcn_mfma_f32_16x16x32_bf16(ah[mt], bh[nt],  acc[mt][nt], 0, 0, 0);
        acc[mt][nt] = __builtin_amdgcn_mfma_f32_16x16x32_bf16(al[mt], bh[nt],  acc[mt][nt], 0, 0, 0);
        acc[mt][nt] = __builtin_amdgcn_mfma_f32_16x16x32_bf16(ah[mt], bl2[nt], acc[mt][nt], 0, 0, 0);
      }
  }

#pragma unroll
  for (int mt = 0; mt < 4; ++mt)
#pragma unroll
    for (int nt = 0; nt < 4; ++nt)
#pragma unroll
      for (int r = 0; r < 4; ++r) {
        const int gm = rbase + wm * 64 + mt * 16 + q * 4 + r;
        const int gn = nbase + wn * 64 + nt * 16 + ln;
        E[gm * 3072 + gn] = acc[mt][nt][r];
      }
}

// ---------------------------------------------------------------------------
// Phase 2: persistent scan, tag-validated h exchange. 256 blocks x 256 thr.
// ---------------------------------------------------------------------------
__global__ void __launch_bounds__(256, 1) rnn_scan(
    const float* __restrict__ E,
    const float* __restrict__ Wmm,
    unsigned* __restrict__ hbuf,     // [2][64][1024] packed (hi | lo<<16), tag in lo[1:0]
    float* __restrict__ out)
{
  __shared__ float part[2][4 * 16 * 33];   // [t&1][kq*16+m][n 32 (+1 pad)]

  const int tid = threadIdx.x;
  const int bg  = blockIdx.x >> 6;      // 0..3 group
  const int cg  = blockIdx.x & 63;      // 0..63 block-in-group
  const int b0  = bg << 4;              // batch base (16 per group)
  const int j0  = cg << 4;              // column base

  const int kq = tid >> 6;              // wave = k-quarter
  const int lane = tid & 63;
  const int q = lane >> 4, ln = lane & 15;

  // --- W_mm fragments, hi/lo bf16, VGPR-resident: [nt][ks] (nt0=a, nt1=c) ---
  short8 wh[2][8], wl[2][8];
#pragma unroll
  for (int nt = 0; nt < 2; ++nt) {
    const int row = (nt ? 1024 + j0 + ln : j0 + ln);
    const float* wp = Wmm + row * 1024 + kq * 256 + q * 8;
#pragma unroll
    for (int ks = 0; ks < 8; ++ks) {
      const float4 f0 = *(const float4*)(wp + ks * 32);
      const float4 f1 = *(const float4*)(wp + ks * 32 + 4);
      float f[8] = {f0.x, f0.y, f0.z, f0.w, f1.x, f1.y, f1.z, f1.w};
      short8 h8, l8;
#pragma unroll
      for (int e = 0; e < 8; ++e) {
        const unsigned short hh = f2bf(f[e]);
        h8[e] = (short)hh;
        l8[e] = (short)f2bf(f[e] - bf2f(hh));
      }
      wh[nt][ks] = h8; wl[nt][ks] = l8;
    }
  }

  // update-phase ownership: thread = (batch-local, col-local)
  const int b_l = tid >> 4, jp = tid & 15;
  const int b = b0 + b_l, j = j0 + jp;

  float h_reg = 0.0f;
  const unsigned long long* hbuf64 = (const unsigned long long*)hbuf;
  // this lane's h fragment base (u64 units): 32 u64 = 256 cols quarter slice
  const unsigned hbase64 = ((unsigned)(b0 + ln)) * 512 + (unsigned)kq * 128 + (unsigned)q * 4;
  // canary: one u64 per lane, one per producer block of this wave's k-quarter
  // (producer ln owns cols [kq*256 + ln*16, +16) -> u64 [kq*128 + ln*8, +8))
  const unsigned cano64  = ((unsigned)(b0 + ln)) * 512 + (unsigned)kq * 128 + (unsigned)ln * 8 + (unsigned)q * 2;

  // E prefetch for t=0 (prefetched one step ahead thereafter)
  int erow = (b * 512) * 3072 + j;
  float ia = E[erow], ic = E[erow + 1024], io = E[erow + 2048];

  for (int t = 0; t < 512; ++t) {
    const int cur = t & 1, nxt = cur ^ 1;
    const unsigned tg = (unsigned)t & 3u;

    // --- canary poll: cheap 1-u64/lane gate, samples each producer once.
    //     Bounded (diagnostic): never trips when sync is correct. ---
    {
      const unsigned long long* cp = hbuf64 + (unsigned)cur * 32768u + cano64;
      int spins = 0;
      for (;;) {
        const unsigned long long c = __hip_atomic_load(
            (unsigned long long*)cp, __ATOMIC_RELAXED, __HIP_MEMORY_SCOPE_SYSTEM);
        const unsigned ok = ((((unsigned)(c >> 16)) & 3u) == tg) &
                            ((((unsigned)(c >> 48)) & 3u) == tg);
        if (__all((int)ok)) break;
        if (++spins > 3000) break;   // diagnostic escape: stale h -> absmax fail
        __builtin_amdgcn_s_sleep(1);
      }
      __atomic_signal_fence(__ATOMIC_ACQUIRE);
    }

    // --- streaming load + MFMA attempt with full per-word tag validation.
    //     On a failed vote (rare after canary): re-zero acc, reload, redo.
    //     Bounded (diagnostic). ---
    const unsigned long long* hrow = hbuf64 + (unsigned)cur * 32768u + hbase64;

    floatx4 acc0, acc1;
    int vspins = 0;
    for (;;) {
      acc0 = (floatx4){0.f, 0.f, 0.f, 0.f};
      acc1 = (floatx4){0.f, 0.f, 0.f, 0.f};
      unsigned ok = 1u;
#pragma unroll
      for (int ks = 0; ks < 8; ++ks) {
        unsigned long long d0 = __hip_atomic_load((unsigned long long*)(hrow + ks * 16 + 0),
                                                  __ATOMIC_RELAXED, __HIP_MEMORY_SCOPE_SYSTEM);
        unsigned long long d1 = __hip_atomic_load((unsigned long long*)(hrow + ks * 16 + 1),
                                                  __ATOMIC_RELAXED, __HIP_MEMORY_SCOPE_SYSTEM);
        unsigned long long d2 = __hip_atomic_load((unsigned long long*)(hrow + ks * 16 + 2),
                                                  __ATOMIC_RELAXED, __HIP_MEMORY_SCOPE_SYSTEM);
        unsigned long long d3 = __hip_atomic_load((unsigned long long*)(hrow + ks * 16 + 3),
                                                  __ATOMIC_RELAXED, __HIP_MEMORY_SCOPE_SYSTEM);
        ok &= (((unsigned)(d0 >> 16) & 3u) == tg) & (((unsigned)(d0 >> 48) & 3u) == tg);
        ok &= (((unsigned)(d1 >> 16) & 3u) == tg) & (((unsigned)(d1 >> 48) & 3u) == tg);
        ok &= (((unsigned)(d2 >> 16) & 3u) == tg) & (((unsigned)(d2 >> 48) & 3u) == tg);
        ok &= (((unsigned)(d3 >> 16) & 3u) == tg) & (((unsigned)(d3 >> 48) & 3u) == tg);
        const unsigned pp[8] = {(unsigned)d0, (unsigned)(d0 >> 32),
                                (unsigned)d1, (unsigned)(d1 >> 32),
                                (unsigned)d2, (unsigned)(d2 >> 32),
                                (unsigned)d3, (unsigned)(d3 >> 32)};
        short8 ah, al;
#pragma unroll
        for (int e = 0; e < 8; ++e) {
          ah[e] = (short)(pp[e] & 0xffffu);
          al[e] = (short)(pp[e] >> 16);
        }
        acc0 = __builtin_amdgcn_mfma_f32_16x16x32_bf16(ah, wh[0][ks], acc0, 0, 0, 0);
        acc0 = __builtin_amdgcn_mfma_f32_16x16x32_bf16(al, wh[0][ks], acc0, 0, 0, 0);
        acc0 = __builtin_amdgcn_mfma_f32_16x16x32_bf16(ah, wl[0][ks], acc0, 0, 0, 0);
        acc1 = __builtin_amdgcn_mfma_f32_16x16x32_bf16(ah, wh[1][ks], acc1, 0, 0, 0);
        acc1 = __builtin_amdgcn_mfma_f32_16x16x32_bf16(al, wh[1][ks], acc1, 0, 0, 0);
        acc1 = __builtin_amdgcn_mfma_f32_16x16x32_bf16(ah, wl[1][ks], acc1, 0, 0, 0);
      }
      if (__all((int)ok)) break;
      if (++vspins > 1000) break;    // diagnostic escape: stale h -> absmax fail
      __builtin_amdgcn_s_sleep(1);
    }

    // C/D layout: col = lane&15 (n-local), row = q*4+r (m = batch-local)
#pragma unroll
    for (int r = 0; r < 4; ++r) {
      part[cur][(kq * 16 + q * 4 + r) * 33 + ln]      = acc0[r];
      part[cur][(kq * 16 + q * 4 + r) * 33 + 16 + ln] = acc1[r];
    }
    __syncthreads();   // the ONLY barrier per step (part[] is ping-ponged)

    const float m_a = part[cur][(0 * 16 + b_l) * 33 + jp]      + part[cur][(1 * 16 + b_l) * 33 + jp]
                    + part[cur][(2 * 16 + b_l) * 33 + jp]      + part[cur][(3 * 16 + b_l) * 33 + jp];
    const float m_c = part[cur][(0 * 16 + b_l) * 33 + 16 + jp] + part[cur][(1 * 16 + b_l) * 33 + 16 + jp]
                    + part[cur][(2 * 16 + b_l) * 33 + 16 + jp] + part[cur][(3 * 16 + b_l) * 33 + 16 + jp];

    const float av = 1.0f + fast_tanh(ia + m_a);
    const float cv = fast_sigmoid(ic + m_c);
    const float hn = cv * h_reg + (1.0f - cv) * fast_tanh(io + av * h_reg);
    h_reg = hn;

    // fire-and-forget tagged store: tag (t+1)&3 in lo's 2 LSBs
    const unsigned short hh = f2bf(hn);
    unsigned short hl = f2bf(hn - bf2f(hh));
    hl = (unsigned short)((hl & 0xFFFCu) | (unsigned)((t + 1) & 3));
    __hip_atomic_store(hbuf + (unsigned)nxt * 65536u + (unsigned)b * 1024u + (unsigned)j,
                       (unsigned)hh | ((unsigned)hl << 16),
                       __ATOMIC_RELAXED, __HIP_MEMORY_SCOPE_SYSTEM);

    // out[] cache-bypassing (keeps L2 clean of dirty lines; E stays resident)
    __hip_atomic_store(out + (unsigned)(b * 512 + t) * 1024u + (unsigned)j, hn,
                       __ATOMIC_RELAXED, __HIP_MEMORY_SCOPE_SYSTEM);

    // E prefetch for t+1 (off the wait path of the next step)
    erow += 3072;
    if (t < 511) {
      ia = E[erow];
      ic = E[erow + 1024];
      io = E[erow + 2048];
    }
  }

  out[33554432 + b * 1024 + j] = h_reg;
}

// ---------------------------------------------------------------------------
extern "C" void kernel_launch(void* const* d_in, const int* in_sizes, int n_in,
                              void* d_out, int out_size, void* d_ws, size_t ws_size,
                              hipStream_t stream)
{
  const float* U   = (const float*)d_in[0];   // (64,512,512)
  const float* Wim = (const float*)d_in[1];   // (3072,512)
  const float* Wmm = (const float*)d_in[2];   // (2048,1024)
  float* out = (float*)d_out;                 // 33,554,432 + 65,536 fp32
  char* ws = (char*)d_ws;

  float* E = (float*)ws;
  unsigned* hbuf = (unsigned*)(ws + WS_HBUF_OFF);

  // zero h ping-pong: h0 = 0 AND tag bits = 0 == expected tag at t=0
  hipMemsetAsync((void*)hbuf, 0, 524288, stream);

  gemm_in_proj<<<dim3(256, 24), dim3(256), 0, stream>>>(U, Wim, E);

  rnn_scan<<<dim3(256), dim3(256), 0, stream>>>(E, Wmm, hbuf, out);
}